// Round 7
// baseline (670.646 us; speedup 1.0000x reference)
//
#include <hip/hip_runtime.h>

#define PGD   10
#define ALPHA 0.15f
#define NTAB  32
#define NTHR  256
#define SPT   4
#define FTHR  256
#define FSPT  4

// ws float layout (identical to rounds 1/3/6):
//   [0,    320)    counts_tab[NTAB][10]
//   [320,  32320)  S_tab[PGD][NTAB][100]
//   [32320,33320)  D_glob[10][100]  (slot s = cumulative D after s+1 steps; 0..8 used)
#define WS_COUNTS 0
#define WS_STAB   320
#define WS_DGLOB  32320
#define WS_ZERO_N 33320

__global__ void k_init(float* __restrict__ ws, float* __restrict__ out) {
    int i = blockIdx.x * blockDim.x + threadIdx.x;
    if (i == 0) out[0] = 0.f;
    int gs = gridDim.x * blockDim.x;
    for (int k = i; k < WS_ZERO_N; k += gs) ws[k] = 0.f;
}

// Load 4 contiguous samples (rows s0..s0+3) as 10 float4 + 1 int4, all hoisted.
__device__ __forceinline__ void load4(const float* __restrict__ logit,
                                      const int* __restrict__ y,
                                      int s0, int B, float a[40], int yc[4]) {
    if (s0 + 4 <= B) {
        const float4* rp = reinterpret_cast<const float4*>(logit + (size_t)s0 * 10);
        float4 q[10];
        #pragma unroll
        for (int i = 0; i < 10; ++i) q[i] = rp[i];
        int4 yv = *reinterpret_cast<const int4*>(y + s0);
        #pragma unroll
        for (int i = 0; i < 10; ++i) {
            a[4 * i + 0] = q[i].x; a[4 * i + 1] = q[i].y;
            a[4 * i + 2] = q[i].z; a[4 * i + 3] = q[i].w;
        }
        yc[0] = yv.x; yc[1] = yv.y; yc[2] = yv.z; yc[3] = yv.w;
    } else {
        #pragma unroll
        for (int k = 0; k < 4; ++k) {
            int idx = s0 + k;
            if (idx < B) {
                yc[k] = y[idx];
                for (int j = 0; j < 10; ++j) a[k * 10 + j] = logit[(size_t)idx * 10 + j];
            } else {
                yc[k] = -1;
                for (int j = 0; j < 10; ++j) a[k * 10 + j] = 0.f;
            }
        }
    }
}

__global__ __launch_bounds__(NTHR) void k_step(
    const float* __restrict__ logit, const int* __restrict__ y,
    float* __restrict__ ws, int B, int t /*1..10*/)
{
    __shared__ float sh_D[100];
    __shared__ float shT[100];
    __shared__ float shCnt[10];
    __shared__ float shCn[10];
    __shared__ float wtab[8][100];   // per-(wave, lane-parity) sub-tables
    __shared__ float ctab[8][10];

    const int tid = threadIdx.x;

    float* counts_tab = ws + WS_COUNTS;
    float* S_tab      = ws + WS_STAB;
    float* D_glob     = ws + WS_DGLOB;

    // ---- zero LDS bins ----
    for (int i = tid; i < 800; i += NTHR) (&wtab[0][0])[i] = 0.f;
    if (t == 1) for (int i = tid; i < 80; i += NTHR) (&ctab[0][0])[i] = 0.f;

    // ---- table phase (t>=2): recompute D_{t-1} (round-6 code, has own syncs) ----
    if (t >= 2) {
        const float* Sg = S_tab + (size_t)(t - 2) * (NTAB * 100);
        if (tid < 10) {
            float s = 0.f;
            #pragma unroll
            for (int k = 0; k < NTAB; ++k) s += counts_tab[k * 10 + tid];
            shCnt[tid] = (s == 0.f) ? 100.f : s;
        }
        if (tid < 100) {
            float s = 0.f;
            #pragma unroll
            for (int k = 0; k < NTAB; ++k) s += Sg[k * 100 + tid];
            shT[tid] = s;
        }
        __syncthreads();
        if (tid < 100) {
            int c = tid / 10, j = tid - c * 10;
            shT[tid] = shT[tid] / shCnt[c] - ((c == j) ? 1.f : 0.f);
        }
        __syncthreads();
        if (tid < 10) {  // column norms (torch-faithful: row c divided by col_norm[c])
            float s = 0.f;
            for (int cc = 0; cc < 10; ++cc) { float g = shT[cc * 10 + tid]; s += g * g; }
            shCn[tid] = sqrtf(s);
        }
        __syncthreads();
        if (tid < 100) {
            int c = tid / 10;
            float sign = (c < 4) ? -1.f : 1.f;   // SIGN_VEC = [-1]*4 + [1]*6
            float g = shT[tid] / shCn[c] * (ALPHA * sign);
            sh_D[tid] = ((t >= 3) ? D_glob[(size_t)(t - 3) * 100 + tid] : 0.f) + g;
        }
        __syncthreads();
        if (blockIdx.x == 0 && tid < 100) D_glob[(size_t)(t - 2) * 100 + tid] = sh_D[tid];
    }
    __syncthreads();   // bins zeroed + sh_D ready (no barriers after this point until flush)

    // ---- hoisted wide loads: 11 independent VMEM ops, no early-exit branch ----
    const int s0 = (blockIdx.x * NTHR + tid) * SPT;
    float a[40];
    int   yc[4];
    load4(logit, y, s0, B, a, yc);

    // ---- process 4 samples ----
    const int sub = ((tid >> 6) << 1) | (tid & 1);  // 0..7
    #pragma unroll
    for (int k = 0; k < SPT; ++k) {
        int c = yc[k];
        if (c < 0) continue;
        float tv[10];
        #pragma unroll
        for (int j = 0; j < 10; ++j) tv[j] = a[k * 10 + j];
        if (t >= 2) {
            #pragma unroll
            for (int j = 0; j < 10; ++j) tv[j] += sh_D[c * 10 + j];
        }
        float m = tv[0];
        #pragma unroll
        for (int j = 1; j < 10; ++j) m = fmaxf(m, tv[j]);
        float s = 0.f;
        #pragma unroll
        for (int j = 0; j < 10; ++j) { tv[j] = __expf(tv[j] - m); s += tv[j]; }
        float r = 1.f / s;
        #pragma unroll
        for (int j = 0; j < 10; ++j) unsafeAtomicAdd(&wtab[sub][c * 10 + j], tv[j] * r);
        if (t == 1) unsafeAtomicAdd(&ctab[sub][c], 1.f);
    }
    __syncthreads();

    // ---- flush block partials to spread global tables ----
    const int tb = blockIdx.x & (NTAB - 1);
    if (tid < 100) {
        float s = 0.f;
        #pragma unroll
        for (int w = 0; w < 8; ++w) s += wtab[w][tid];
        unsafeAtomicAdd(&S_tab[(size_t)(t - 1) * (NTAB * 100) + (size_t)tb * 100 + tid], s);
    }
    if (t == 1 && tid < 10) {
        float s = 0.f;
        #pragma unroll
        for (int w = 0; w < 8; ++w) s += ctab[w][tid];
        unsafeAtomicAdd(&counts_tab[tb * 10 + tid], s);
    }
}

__global__ __launch_bounds__(FTHR) void k_final(
    const float* __restrict__ logit, const int* __restrict__ y,
    const int* __restrict__ label_freq,
    float* __restrict__ out, float* __restrict__ ws, int B)
{
    __shared__ float Dall[PGD][100];
    __shared__ float shT[100];
    __shared__ float shCnt[10];
    __shared__ float shCn[10];
    __shared__ int   lf[10];
    __shared__ float wsum[4];

    const int tid = threadIdx.x;

    float* counts_tab = ws + WS_COUNTS;
    float* S_tab      = ws + WS_STAB;
    float* D_glob     = ws + WS_DGLOB;

    // ---- D_10 from S_tab[9] + D_glob[8]; load D_glob[0..8] (round-6 code) ----
    {
        const float* Sg = S_tab + (size_t)9 * (NTAB * 100);
        if (tid < 10) {
            float s = 0.f;
            #pragma unroll
            for (int k = 0; k < NTAB; ++k) s += counts_tab[k * 10 + tid];
            shCnt[tid] = (s == 0.f) ? 100.f : s;
        }
        if (tid < 100) {
            float s = 0.f;
            #pragma unroll
            for (int k = 0; k < NTAB; ++k) s += Sg[k * 100 + tid];
            shT[tid] = s;
        }
        __syncthreads();
        if (tid < 100) {
            int c = tid / 10, j = tid - c * 10;
            shT[tid] = shT[tid] / shCnt[c] - ((c == j) ? 1.f : 0.f);
        }
        __syncthreads();
        if (tid < 10) {
            float s = 0.f;
            for (int cc = 0; cc < 10; ++cc) { float g = shT[cc * 10 + tid]; s += g * g; }
            shCn[tid] = sqrtf(s);
        }
        __syncthreads();
        if (tid < 100) {
            int c = tid / 10;
            float sign = (c < 4) ? -1.f : 1.f;
            float g = shT[tid] / shCn[c] * (ALPHA * sign);
            Dall[9][tid] = D_glob[8 * 100 + tid] + g;
        }
        for (int i = tid; i < 900; i += FTHR) Dall[i / 100][i % 100] = D_glob[i];
        if (tid < 10) lf[tid] = label_freq[tid];
        __syncthreads();
    }

    // ---- hoisted wide loads ----
    const int s0 = (blockIdx.x * FTHR + tid) * FSPT;
    float a[40];
    int   yc[4];
    load4(logit, y, s0, B, a, yc);

    // ---- outputs + CE ----
    float* news_out = out + 1;
    float* copy_out = out + 1 + (size_t)B * 10;
    float acc = 0.f;
    #pragma unroll
    for (int k = 0; k < FSPT; ++k) {
        int idx = s0 + k;
        if (idx >= B || yc[k] < 0) continue;
        int c = yc[k];
        int sel = lf[c];                       // state after sel+1 steps == Dall[sel]
        float nv[10];
        #pragma unroll
        for (int j = 0; j < 10; ++j) nv[j] = a[k * 10 + j] + Dall[sel][c * 10 + j];
        float2* np = reinterpret_cast<float2*>(news_out + (size_t)idx * 10);
        float2* cp = reinterpret_cast<float2*>(copy_out + (size_t)idx * 10);
        #pragma unroll
        for (int q = 0; q < 5; ++q) {
            np[q] = make_float2(nv[2 * q], nv[2 * q + 1]);
            cp[q] = make_float2(a[k * 10 + 2 * q], a[k * 10 + 2 * q + 1]);
        }
        float m = nv[0];
        #pragma unroll
        for (int j = 1; j < 10; ++j) m = fmaxf(m, nv[j]);
        float s = 0.f;
        #pragma unroll
        for (int j = 0; j < 10; ++j) s += __expf(nv[j] - m);
        acc += __logf(s) + m - nv[c];
    }
    #pragma unroll
    for (int off = 32; off > 0; off >>= 1) acc += __shfl_down(acc, off);
    if ((tid & 63) == 0) wsum[tid >> 6] = acc;
    __syncthreads();
    if (tid == 0)
        unsafeAtomicAdd(out, (wsum[0] + wsum[1] + wsum[2] + wsum[3]) / (float)B);
}

extern "C" void kernel_launch(void* const* d_in, const int* in_sizes, int n_in,
                              void* d_out, int out_size, void* d_ws, size_t ws_size,
                              hipStream_t stream) {
    const float* logit = (const float*)d_in[0];
    const int*   yy    = (const int*)d_in[1];
    const int*   lf    = (const int*)d_in[2];
    float* out = (float*)d_out;
    float* ws  = (float*)d_ws;
    int B = in_sizes[0] / 10;

    int blocks  = (B + NTHR * SPT - 1) / (NTHR * SPT);    // 1024 for B = 1M
    int fblocks = (B + FTHR * FSPT - 1) / (FTHR * FSPT);  // 1024

    hipLaunchKernelGGL(k_init, dim3(64), dim3(256), 0, stream, ws, out);
    for (int t = 1; t <= PGD; ++t)
        hipLaunchKernelGGL(k_step, dim3(blocks), dim3(NTHR), 0, stream,
                           logit, yy, ws, B, t);
    hipLaunchKernelGGL(k_final, dim3(fblocks), dim3(FTHR), 0, stream,
                       logit, yy, lf, out, ws, B);
}

// Round 8
// 662.787 us; speedup vs baseline: 1.0119x; 1.0119x over previous
//
#include <hip/hip_runtime.h>

#define PGD   10
#define ALPHA 0.15f
#define NTAB  32
#define NTHR  256
#define TSAMP 1024          // samples staged per block (40 KB tile)
#define NSUB  8

// ws float layout (identical to rounds 1/3/6/7):
//   [0,    320)    counts_tab[NTAB][10]
//   [320,  32320)  S_tab[PGD][NTAB][100]
//   [32320,33320)  D_glob[10][100]  (slot s = cumulative D after s+1 steps; 0..8 used)
#define WS_COUNTS 0
#define WS_STAB   320
#define WS_DGLOB  32320
#define WS_ZERO_N 33320

__global__ void k_init(float* __restrict__ ws, float* __restrict__ out) {
    int i = blockIdx.x * blockDim.x + threadIdx.x;
    if (i == 0) out[0] = 0.f;
    int gs = gridDim.x * blockDim.x;
    for (int k = i; k < WS_ZERO_N; k += gs) ws[k] = 0.f;
}

// fp32 table step (identical math to the passing rounds).
__device__ __forceinline__ void table_phase(
    const float* __restrict__ Sg, const float* __restrict__ counts_tab,
    const float* __restrict__ Dprev,  // nullptr == zeros
    float* shT, float* shCnt, float* shCn, float* shD_out, int tid)
{
    if (tid < 10) {
        float s = 0.f;
        #pragma unroll
        for (int k = 0; k < NTAB; ++k) s += counts_tab[k * 10 + tid];
        shCnt[tid] = (s == 0.f) ? 100.f : s;
    }
    if (tid < 100) {
        float s = 0.f;
        #pragma unroll
        for (int k = 0; k < NTAB; ++k) s += Sg[k * 100 + tid];
        shT[tid] = s;
    }
    __syncthreads();
    if (tid < 100) {
        int c = tid / 10, j = tid - c * 10;
        shT[tid] = shT[tid] / shCnt[c] - ((c == j) ? 1.f : 0.f);
    }
    __syncthreads();
    if (tid < 10) {  // column norms (torch-faithful: row c divided by col_norm[c])
        float s = 0.f;
        for (int cc = 0; cc < 10; ++cc) { float g = shT[cc * 10 + tid]; s += g * g; }
        shCn[tid] = sqrtf(s);
    }
    __syncthreads();
    if (tid < 100) {
        int c = tid / 10;
        float sign = (c < 4) ? -1.f : 1.f;   // SIGN_VEC = [-1]*4 + [1]*6
        float g = shT[tid] / shCn[c] * (ALPHA * sign);
        shD_out[tid] = (Dprev ? Dprev[tid] : 0.f) + g;
    }
    __syncthreads();
}

// Coalesced tile load: 10 lane-linear float4 + 1 int4 per thread.
__device__ __forceinline__ void load_tile(const float* __restrict__ logit,
                                          const int* __restrict__ y,
                                          size_t fbase, size_t ftot, int B,
                                          int tid, int blk, float4 q[10], int4& yq)
{
    #pragma unroll
    for (int i = 0; i < 10; ++i) {
        size_t fi = fbase + (size_t)(tid + i * NTHR) * 4;
        if (fi + 4 <= ftot) {
            q[i] = *reinterpret_cast<const float4*>(logit + fi);
        } else {
            float e[4];
            #pragma unroll
            for (int e2 = 0; e2 < 4; ++e2) e[e2] = (fi + e2 < ftot) ? logit[fi + e2] : 0.f;
            q[i] = make_float4(e[0], e[1], e[2], e[3]);
        }
    }
    int yi = blk * TSAMP + tid * 4;
    if (yi + 4 <= B) {
        yq = *reinterpret_cast<const int4*>(y + yi);
    } else {
        yq.x = (yi     < B) ? y[yi]     : 0;
        yq.y = (yi + 1 < B) ? y[yi + 1] : 0;
        yq.z = (yi + 2 < B) ? y[yi + 2] : 0;
        yq.w = (yi + 3 < B) ? y[yi + 3] : 0;
    }
}

__global__ __launch_bounds__(NTHR) void k_step(
    const float* __restrict__ logit, const int* __restrict__ y,
    float* __restrict__ ws, int B, int t /*1..10*/)
{
    __shared__ float tile[TSAMP * 10];   // 40 KB
    __shared__ int   yt[TSAMP];          // 4 KB
    __shared__ float wtab[NSUB][100];
    __shared__ float ctab[NSUB][10];
    __shared__ float sh_D[100];
    __shared__ float shT[100];
    __shared__ float shCnt[10];
    __shared__ float shCn[10];

    const int tid = threadIdx.x;

    float* counts_tab = ws + WS_COUNTS;
    float* S_tab      = ws + WS_STAB;
    float* D_glob     = ws + WS_DGLOB;

    // ---- phase A: coalesced global loads into regs (8 lines/instr) ----
    const size_t fbase = (size_t)blockIdx.x * (TSAMP * 10);
    const size_t ftot  = (size_t)B * 10;
    float4 q[10];
    int4 yq;
    load_tile(logit, y, fbase, ftot, B, tid, blockIdx.x, q, yq);

    // zero LDS bins (overlaps load latency)
    for (int i = tid; i < NSUB * 100; i += NTHR) (&wtab[0][0])[i] = 0.f;
    if (t == 1) for (int i = tid; i < NSUB * 10; i += NTHR) (&ctab[0][0])[i] = 0.f;

    // ---- table phase (t>=2): recompute D_{t-1}, identical in every block ----
    if (t >= 2) {
        table_phase(S_tab + (size_t)(t - 2) * (NTAB * 100), counts_tab,
                    (t >= 3) ? (D_glob + (size_t)(t - 3) * 100) : nullptr,
                    shT, shCnt, shCn, sh_D, tid);
        if (blockIdx.x == 0 && tid < 100) D_glob[(size_t)(t - 2) * 100 + tid] = sh_D[tid];
    }

    // ---- stage tile to LDS (lane-linear b128, no conflicts beyond inherent) ----
    float4* tp = reinterpret_cast<float4*>(tile);
    #pragma unroll
    for (int i = 0; i < 10; ++i) tp[tid + i * NTHR] = q[i];
    reinterpret_cast<int4*>(yt)[tid] = yq;
    __syncthreads();

    // ---- compute: strided rows (lane->consecutive rows, 4-way LDS max) ----
    const int sub = ((tid >> 6) << 1) | (tid & 1);  // 0..7
    #pragma unroll
    for (int k = 0; k < 4; ++k) {
        int sl = tid + k * NTHR;
        int gi = blockIdx.x * TSAMP + sl;
        if (gi >= B) break;
        int c = yt[sl];
        const float2* rp = reinterpret_cast<const float2*>(tile + sl * 10);
        float tv[10];
        #pragma unroll
        for (int h = 0; h < 5; ++h) { float2 v = rp[h]; tv[2 * h] = v.x; tv[2 * h + 1] = v.y; }
        if (t >= 2) {
            #pragma unroll
            for (int j = 0; j < 10; ++j) tv[j] += sh_D[c * 10 + j];
        }
        float m = tv[0];
        #pragma unroll
        for (int j = 1; j < 10; ++j) m = fmaxf(m, tv[j]);
        float s = 0.f;
        #pragma unroll
        for (int j = 0; j < 10; ++j) { tv[j] = __expf(tv[j] - m); s += tv[j]; }
        float r = 1.f / s;
        #pragma unroll
        for (int j = 0; j < 10; ++j) unsafeAtomicAdd(&wtab[sub][c * 10 + j], tv[j] * r);
        if (t == 1) unsafeAtomicAdd(&ctab[sub][c], 1.f);
    }
    __syncthreads();

    // ---- flush block partials to spread global tables ----
    const int tb = blockIdx.x & (NTAB - 1);
    if (tid < 100) {
        float s = 0.f;
        #pragma unroll
        for (int w = 0; w < NSUB; ++w) s += wtab[w][tid];
        unsafeAtomicAdd(&S_tab[(size_t)(t - 1) * (NTAB * 100) + (size_t)tb * 100 + tid], s);
    }
    if (t == 1 && tid < 10) {
        float s = 0.f;
        #pragma unroll
        for (int w = 0; w < NSUB; ++w) s += ctab[w][tid];
        unsafeAtomicAdd(&counts_tab[tb * 10 + tid], s);
    }
}

__global__ __launch_bounds__(NTHR) void k_final(
    const float* __restrict__ logit, const int* __restrict__ y,
    const int* __restrict__ label_freq,
    float* __restrict__ out, float* __restrict__ ws, int B)
{
    __shared__ float tile[TSAMP * 10];   // 40 KB, reused in-place for news
    __shared__ int   yt[TSAMP];
    __shared__ float Dall[PGD][100];
    __shared__ float shT[100];
    __shared__ float shCnt[10];
    __shared__ float shCn[10];
    __shared__ int   lf[10];
    __shared__ float wsum[4];

    const int tid = threadIdx.x;

    float* counts_tab = ws + WS_COUNTS;
    float* S_tab      = ws + WS_STAB;
    float* D_glob     = ws + WS_DGLOB;

    // ---- phase A: coalesced loads ----
    const size_t fbase = (size_t)blockIdx.x * (TSAMP * 10);
    const size_t ftot  = (size_t)B * 10;
    float4 q[10];
    int4 yq;
    load_tile(logit, y, fbase, ftot, B, tid, blockIdx.x, q, yq);

    // ---- D_10 from S_tab[9] + D_glob[8]; Dall[0..8] from D_glob ----
    table_phase(S_tab + (size_t)9 * (NTAB * 100), counts_tab, D_glob + 8 * 100,
                shT, shCnt, shCn, &Dall[9][0], tid);
    for (int i = tid; i < 900; i += NTHR) Dall[i / 100][i % 100] = D_glob[i];
    if (tid < 10) lf[tid] = label_freq[tid];

    // ---- stage tile ----
    float4* tp = reinterpret_cast<float4*>(tile);
    #pragma unroll
    for (int i = 0; i < 10; ++i) tp[tid + i * NTHR] = q[i];
    reinterpret_cast<int4*>(yt)[tid] = yq;
    __syncthreads();

    const int vfloat = (int)((ftot - fbase < (size_t)(TSAMP * 10)) ? (ftot - fbase)
                                                                   : (size_t)(TSAMP * 10));
    float* news_out = out + 1;
    float* copy_out = out + 1 + ftot;

    // ---- copy-store: lane-linear coalesced dwords straight from the tile ----
    for (int m = tid; m < vfloat; m += NTHR) copy_out[fbase + m] = tile[m];
    __syncthreads();   // all copy reads done before in-place overwrite

    // ---- compute rows (strided), overwrite tile in place with news ----
    float acc = 0.f;
    #pragma unroll
    for (int k = 0; k < 4; ++k) {
        int sl = tid + k * NTHR;
        int gi = blockIdx.x * TSAMP + sl;
        if (gi >= B) break;
        int c = yt[sl];
        int sel = lf[c];                     // state after sel+1 steps == Dall[sel]
        float2* rp = reinterpret_cast<float2*>(tile + sl * 10);
        float nv[10];
        #pragma unroll
        for (int h = 0; h < 5; ++h) {
            float2 v = rp[h];
            nv[2 * h]     = v.x + Dall[sel][c * 10 + 2 * h];
            nv[2 * h + 1] = v.y + Dall[sel][c * 10 + 2 * h + 1];
        }
        #pragma unroll
        for (int h = 0; h < 5; ++h) rp[h] = make_float2(nv[2 * h], nv[2 * h + 1]);
        float m = nv[0];
        #pragma unroll
        for (int j = 1; j < 10; ++j) m = fmaxf(m, nv[j]);
        float s = 0.f;
        #pragma unroll
        for (int j = 0; j < 10; ++j) s += __expf(nv[j] - m);
        acc += __logf(s) + m - nv[c];
    }
    __syncthreads();   // news tile complete

    // ---- news-store: lane-linear coalesced dwords ----
    for (int m = tid; m < vfloat; m += NTHR) news_out[fbase + m] = tile[m];

    // ---- CE reduce ----
    #pragma unroll
    for (int off = 32; off > 0; off >>= 1) acc += __shfl_down(acc, off);
    if ((tid & 63) == 0) wsum[tid >> 6] = acc;
    __syncthreads();
    if (tid == 0)
        unsafeAtomicAdd(out, (wsum[0] + wsum[1] + wsum[2] + wsum[3]) / (float)B);
}

extern "C" void kernel_launch(void* const* d_in, const int* in_sizes, int n_in,
                              void* d_out, int out_size, void* d_ws, size_t ws_size,
                              hipStream_t stream) {
    const float* logit = (const float*)d_in[0];
    const int*   yy    = (const int*)d_in[1];
    const int*   lf    = (const int*)d_in[2];
    float* out = (float*)d_out;
    float* ws  = (float*)d_ws;
    int B = in_sizes[0] / 10;

    int blocks = (B + TSAMP - 1) / TSAMP;   // 1024 for B = 1M

    hipLaunchKernelGGL(k_init, dim3(64), dim3(256), 0, stream, ws, out);
    for (int t = 1; t <= PGD; ++t)
        hipLaunchKernelGGL(k_step, dim3(blocks), dim3(NTHR), 0, stream,
                           logit, yy, ws, B, t);
    hipLaunchKernelGGL(k_final, dim3(blocks), dim3(NTHR), 0, stream,
                       logit, yy, lf, out, ws, B);
}

// Round 9
// 648.305 us; speedup vs baseline: 1.0345x; 1.0223x over previous
//
#include <hip/hip_runtime.h>

#define PGD   10
#define ALPHA 0.15f
#define NTAB  32
#define NTHR  256
#define SPT   4
#define TSAMP (NTHR * SPT)   // 1024 samples per tile
#define NSUB  8

// ws float layout (identical to all passing rounds):
//   [0,    320)    counts_tab[NTAB][10]
//   [320,  32320)  S_tab[PGD][NTAB][100]
//   [32320,33320)  D_glob[10][100]  (slot s = cumulative D after s+1 steps; 0..8 used)
#define WS_COUNTS 0
#define WS_STAB   320
#define WS_DGLOB  32320
#define WS_ZERO_N 33320

// Bijective XCD swizzle (m204): XCD (bid&7) always gets the same contiguous
// tile range across all dispatches -> input slice stays in that XCD's L2.
__device__ __forceinline__ int swz_tile(int bid, int nblk) {
    int q = nblk >> 3, r = nblk & 7;
    int xcd = bid & 7, idx = bid >> 3;
    return (xcd < r ? xcd * (q + 1) : r * (q + 1) + (xcd - r) * q) + idx;
}

__global__ void k_init(float* __restrict__ ws, float* __restrict__ out) {
    int i = blockIdx.x * blockDim.x + threadIdx.x;
    if (i == 0) out[0] = 0.f;
    int gs = gridDim.x * blockDim.x;
    for (int k = i; k < WS_ZERO_N; k += gs) ws[k] = 0.f;
}

// fp32 table step (identical math to the passing rounds).
__device__ __forceinline__ void table_phase(
    const float* __restrict__ Sg, const float* __restrict__ counts_tab,
    const float* __restrict__ Dprev,  // nullptr == zeros
    float* shT, float* shCnt, float* shCn, float* shD_out, int tid)
{
    if (tid < 10) {
        float s = 0.f;
        #pragma unroll
        for (int k = 0; k < NTAB; ++k) s += counts_tab[k * 10 + tid];
        shCnt[tid] = (s == 0.f) ? 100.f : s;
    }
    if (tid < 100) {
        float s = 0.f;
        #pragma unroll
        for (int k = 0; k < NTAB; ++k) s += Sg[k * 100 + tid];
        shT[tid] = s;
    }
    __syncthreads();
    if (tid < 100) {
        int c = tid / 10, j = tid - c * 10;
        shT[tid] = shT[tid] / shCnt[c] - ((c == j) ? 1.f : 0.f);
    }
    __syncthreads();
    if (tid < 10) {  // column norms (torch-faithful: row c divided by col_norm[c])
        float s = 0.f;
        for (int cc = 0; cc < 10; ++cc) { float g = shT[cc * 10 + tid]; s += g * g; }
        shCn[tid] = sqrtf(s);
    }
    __syncthreads();
    if (tid < 100) {
        int c = tid / 10;
        float sign = (c < 4) ? -1.f : 1.f;   // SIGN_VEC = [-1]*4 + [1]*6
        float g = shT[tid] / shCn[c] * (ALPHA * sign);
        shD_out[tid] = (Dprev ? Dprev[tid] : 0.f) + g;
    }
    __syncthreads();
}

// Load 4 contiguous samples (rows s0..s0+3) as 10 float4 + 1 int4, all hoisted.
__device__ __forceinline__ void load4(const float* __restrict__ logit,
                                      const int* __restrict__ y,
                                      int s0, int B, float a[40], int yc[4]) {
    if (s0 + 4 <= B) {
        const float4* rp = reinterpret_cast<const float4*>(logit + (size_t)s0 * 10);
        float4 q[10];
        #pragma unroll
        for (int i = 0; i < 10; ++i) q[i] = rp[i];
        int4 yv = *reinterpret_cast<const int4*>(y + s0);
        #pragma unroll
        for (int i = 0; i < 10; ++i) {
            a[4 * i + 0] = q[i].x; a[4 * i + 1] = q[i].y;
            a[4 * i + 2] = q[i].z; a[4 * i + 3] = q[i].w;
        }
        yc[0] = yv.x; yc[1] = yv.y; yc[2] = yv.z; yc[3] = yv.w;
    } else {
        #pragma unroll
        for (int k = 0; k < 4; ++k) {
            int idx = s0 + k;
            if (idx < B) {
                yc[k] = y[idx];
                for (int j = 0; j < 10; ++j) a[k * 10 + j] = logit[(size_t)idx * 10 + j];
            } else {
                yc[k] = -1;
                for (int j = 0; j < 10; ++j) a[k * 10 + j] = 0.f;
            }
        }
    }
}

__global__ __launch_bounds__(NTHR) void k_step(
    const float* __restrict__ logit, const int* __restrict__ y,
    float* __restrict__ ws, int B, int t /*1..10*/)
{
    __shared__ float sh_D[100];
    __shared__ float shT[100];
    __shared__ float shCnt[10];
    __shared__ float shCn[10];
    __shared__ float wtab[NSUB][100];
    __shared__ float ctab[NSUB][10];

    const int tid = threadIdx.x;
    const int tile = swz_tile(blockIdx.x, gridDim.x);

    float* counts_tab = ws + WS_COUNTS;
    float* S_tab      = ws + WS_STAB;
    float* D_glob     = ws + WS_DGLOB;

    // ---- hoisted wide loads from THIS XCD's pinned slice ----
    const int s0 = tile * TSAMP + tid * SPT;
    float a[40];
    int   yc[4];
    load4(logit, y, s0, B, a, yc);

    // ---- zero LDS bins (overlaps load flight) ----
    for (int i = tid; i < NSUB * 100; i += NTHR) (&wtab[0][0])[i] = 0.f;
    if (t == 1) for (int i = tid; i < NSUB * 10; i += NTHR) (&ctab[0][0])[i] = 0.f;

    // ---- table phase (t>=2): recompute D_{t-1}, identical in every block ----
    if (t >= 2) {
        table_phase(S_tab + (size_t)(t - 2) * (NTAB * 100), counts_tab,
                    (t >= 3) ? (D_glob + (size_t)(t - 3) * 100) : nullptr,
                    shT, shCnt, shCn, sh_D, tid);
        if (blockIdx.x == 0 && tid < 100) D_glob[(size_t)(t - 2) * 100 + tid] = sh_D[tid];
    }
    __syncthreads();

    // ---- process 4 samples from registers ----
    const int sub = ((tid >> 6) << 1) | (tid & 1);  // 0..7
    #pragma unroll
    for (int k = 0; k < SPT; ++k) {
        int c = yc[k];
        if (c < 0) continue;
        float tv[10];
        #pragma unroll
        for (int j = 0; j < 10; ++j) tv[j] = a[k * 10 + j];
        if (t >= 2) {
            #pragma unroll
            for (int j = 0; j < 10; ++j) tv[j] += sh_D[c * 10 + j];
        }
        float m = tv[0];
        #pragma unroll
        for (int j = 1; j < 10; ++j) m = fmaxf(m, tv[j]);
        float s = 0.f;
        #pragma unroll
        for (int j = 0; j < 10; ++j) { tv[j] = __expf(tv[j] - m); s += tv[j]; }
        float r = 1.f / s;
        #pragma unroll
        for (int j = 0; j < 10; ++j) unsafeAtomicAdd(&wtab[sub][c * 10 + j], tv[j] * r);
        if (t == 1) unsafeAtomicAdd(&ctab[sub][c], 1.f);
    }
    __syncthreads();

    // ---- flush block partials to spread global tables ----
    const int tb = blockIdx.x & (NTAB - 1);
    if (tid < 100) {
        float s = 0.f;
        #pragma unroll
        for (int w = 0; w < NSUB; ++w) s += wtab[w][tid];
        unsafeAtomicAdd(&S_tab[(size_t)(t - 1) * (NTAB * 100) + (size_t)tb * 100 + tid], s);
    }
    if (t == 1 && tid < 10) {
        float s = 0.f;
        #pragma unroll
        for (int w = 0; w < NSUB; ++w) s += ctab[w][tid];
        unsafeAtomicAdd(&counts_tab[tb * 10 + tid], s);
    }
}

__global__ __launch_bounds__(NTHR) void k_final(
    const float* __restrict__ logit, const int* __restrict__ y,
    const int* __restrict__ label_freq,
    float* __restrict__ out, float* __restrict__ ws, int B)
{
    __shared__ float tile_f[TSAMP * 10];   // 40 KB, reused in-place for news
    __shared__ int   yt[TSAMP];
    __shared__ float Dall[PGD][100];
    __shared__ float shT[100];
    __shared__ float shCnt[10];
    __shared__ float shCn[10];
    __shared__ int   lf[10];
    __shared__ float wsum[4];

    const int tid = threadIdx.x;
    const int tile = swz_tile(blockIdx.x, gridDim.x);

    float* counts_tab = ws + WS_COUNTS;
    float* S_tab      = ws + WS_STAB;
    float* D_glob     = ws + WS_DGLOB;

    // ---- coalesced lane-linear loads of this tile (hits pinned L2 slice) ----
    const size_t fbase = (size_t)tile * (TSAMP * 10);
    const size_t ftot  = (size_t)B * 10;
    float4 q[10];
    int4 yq;
    #pragma unroll
    for (int i = 0; i < 10; ++i) {
        size_t fi = fbase + (size_t)(tid + i * NTHR) * 4;
        if (fi + 4 <= ftot) {
            q[i] = *reinterpret_cast<const float4*>(logit + fi);
        } else {
            float e[4];
            #pragma unroll
            for (int e2 = 0; e2 < 4; ++e2) e[e2] = (fi + e2 < ftot) ? logit[fi + e2] : 0.f;
            q[i] = make_float4(e[0], e[1], e[2], e[3]);
        }
    }
    {
        int yi = tile * TSAMP + tid * 4;
        if (yi + 4 <= B) {
            yq = *reinterpret_cast<const int4*>(y + yi);
        } else {
            yq.x = (yi     < B) ? y[yi]     : 0;
            yq.y = (yi + 1 < B) ? y[yi + 1] : 0;
            yq.z = (yi + 2 < B) ? y[yi + 2] : 0;
            yq.w = (yi + 3 < B) ? y[yi + 3] : 0;
        }
    }

    // ---- D_10 from S_tab[9] + D_glob[8]; Dall[0..8] from D_glob ----
    table_phase(S_tab + (size_t)9 * (NTAB * 100), counts_tab, D_glob + 8 * 100,
                shT, shCnt, shCn, &Dall[9][0], tid);
    for (int i = tid; i < 900; i += NTHR) Dall[i / 100][i % 100] = D_glob[i];
    if (tid < 10) lf[tid] = label_freq[tid];

    // ---- stage tile ----
    float4* tp = reinterpret_cast<float4*>(tile_f);
    #pragma unroll
    for (int i = 0; i < 10; ++i) tp[tid + i * NTHR] = q[i];
    reinterpret_cast<int4*>(yt)[tid] = yq;
    __syncthreads();

    const int vfloat = (int)((ftot - fbase < (size_t)(TSAMP * 10)) ? (ftot - fbase)
                                                                   : (size_t)(TSAMP * 10));
    float* news_out = out + 1;
    float* copy_out = out + 1 + ftot;

    // ---- copy-store: lane-linear coalesced dwords straight from the tile ----
    for (int m = tid; m < vfloat; m += NTHR) copy_out[fbase + m] = tile_f[m];
    __syncthreads();   // all copy reads done before in-place overwrite

    // ---- compute rows (strided), overwrite tile in place with news ----
    float acc = 0.f;
    #pragma unroll
    for (int k = 0; k < SPT; ++k) {
        int sl = tid + k * NTHR;
        int gi = tile * TSAMP + sl;
        if (gi >= B) break;
        int c = yt[sl];
        int sel = lf[c];                     // state after sel+1 steps == Dall[sel]
        float2* rp = reinterpret_cast<float2*>(tile_f + sl * 10);
        float nv[10];
        #pragma unroll
        for (int h = 0; h < 5; ++h) {
            float2 v = rp[h];
            nv[2 * h]     = v.x + Dall[sel][c * 10 + 2 * h];
            nv[2 * h + 1] = v.y + Dall[sel][c * 10 + 2 * h + 1];
        }
        #pragma unroll
        for (int h = 0; h < 5; ++h) rp[h] = make_float2(nv[2 * h], nv[2 * h + 1]);
        float m = nv[0];
        #pragma unroll
        for (int j = 1; j < 10; ++j) m = fmaxf(m, nv[j]);
        float s = 0.f;
        #pragma unroll
        for (int j = 0; j < 10; ++j) s += __expf(nv[j] - m);
        acc += __logf(s) + m - nv[c];
    }
    __syncthreads();   // news tile complete

    // ---- news-store: lane-linear coalesced dwords ----
    for (int m = tid; m < vfloat; m += NTHR) news_out[fbase + m] = tile_f[m];

    // ---- CE reduce ----
    #pragma unroll
    for (int off = 32; off > 0; off >>= 1) acc += __shfl_down(acc, off);
    if ((tid & 63) == 0) wsum[tid >> 6] = acc;
    __syncthreads();
    if (tid == 0)
        unsafeAtomicAdd(out, (wsum[0] + wsum[1] + wsum[2] + wsum[3]) / (float)B);
}

extern "C" void kernel_launch(void* const* d_in, const int* in_sizes, int n_in,
                              void* d_out, int out_size, void* d_ws, size_t ws_size,
                              hipStream_t stream) {
    const float* logit = (const float*)d_in[0];
    const int*   yy    = (const int*)d_in[1];
    const int*   lf    = (const int*)d_in[2];
    float* out = (float*)d_out;
    float* ws  = (float*)d_ws;
    int B = in_sizes[0] / 10;

    int blocks = (B + TSAMP - 1) / TSAMP;   // 1024 for B = 1M

    hipLaunchKernelGGL(k_init, dim3(64), dim3(256), 0, stream, ws, out);
    for (int t = 1; t <= PGD; ++t)
        hipLaunchKernelGGL(k_step, dim3(blocks), dim3(NTHR), 0, stream,
                           logit, yy, ws, B, t);
    hipLaunchKernelGGL(k_final, dim3(blocks), dim3(NTHR), 0, stream,
                       logit, yy, lf, out, ws, B);
}

// Round 10
// 645.709 us; speedup vs baseline: 1.0386x; 1.0040x over previous
//
#include <hip/hip_runtime.h>
#include <hip/hip_cooperative_groups.h>

namespace cg = cooperative_groups;

#define PGD   10
#define ALPHA 0.15f
#define NTAB  32
#define NSUB  8

// ---- fused kernel geometry ----
#define FTH   512           // threads/block
#define FSP   8             // samples/thread (contiguous rows)
#define FTS   (FTH * FSP)   // 4096 samples per block

// ---- fallback (round-9) geometry ----
#define NTHR  256
#define SPT   4
#define TSAMP (NTHR * SPT)

// ws float layout (identical to all passing rounds):
//   [0,    320)    counts_tab[NTAB][10]
//   [320,  32320)  S_tab[PGD][NTAB][100]
//   [32320,33320)  D_glob[10][100]  (slot s = cumulative D after s+1 steps)
#define WS_COUNTS 0
#define WS_STAB   320
#define WS_DGLOB  32320
#define WS_ZERO_N 33320

__global__ void k_init(float* __restrict__ ws, float* __restrict__ out) {
    int i = blockIdx.x * blockDim.x + threadIdx.x;
    if (i == 0) out[0] = 0.f;
    int gs = gridDim.x * blockDim.x;
    for (int k = i; k < WS_ZERO_N; k += gs) ws[k] = 0.f;
}

// fp32 table step (identical math to all passing rounds).
__device__ __forceinline__ void table_phase(
    const float* __restrict__ Sg, const float* __restrict__ counts_tab,
    const float* Dprev,  // nullptr == zeros (may be LDS or global)
    float* shT, float* shCnt, float* shCn, float* shD_out, int tid)
{
    if (tid < 10) {
        float s = 0.f;
        #pragma unroll
        for (int k = 0; k < NTAB; ++k) s += counts_tab[k * 10 + tid];
        shCnt[tid] = (s == 0.f) ? 100.f : s;
    }
    if (tid < 100) {
        float s = 0.f;
        #pragma unroll
        for (int k = 0; k < NTAB; ++k) s += Sg[k * 100 + tid];
        shT[tid] = s;
    }
    __syncthreads();
    if (tid < 100) {
        int c = tid / 10, j = tid - c * 10;
        shT[tid] = shT[tid] / shCnt[c] - ((c == j) ? 1.f : 0.f);
    }
    __syncthreads();
    if (tid < 10) {  // column norms (torch-faithful: row c divided by col_norm[c])
        float s = 0.f;
        for (int cc = 0; cc < 10; ++cc) { float g = shT[cc * 10 + tid]; s += g * g; }
        shCn[tid] = sqrtf(s);
    }
    __syncthreads();
    if (tid < 100) {
        int c = tid / 10;
        float sign = (c < 4) ? -1.f : 1.f;   // SIGN_VEC = [-1]*4 + [1]*6
        float g = shT[tid] / shCn[c] * (ALPHA * sign);
        shD_out[tid] = (Dprev ? Dprev[tid] : 0.f) + g;
    }
    __syncthreads();
}

// Load 4 contiguous samples as 10 float4 + 1 int4, hoisted.
__device__ __forceinline__ void load4(const float* __restrict__ logit,
                                      const int* __restrict__ y,
                                      int s0, int B, float* a, int* yc) {
    if (s0 + 4 <= B) {
        const float4* rp = reinterpret_cast<const float4*>(logit + (size_t)s0 * 10);
        float4 q[10];
        #pragma unroll
        for (int i = 0; i < 10; ++i) q[i] = rp[i];
        int4 yv = *reinterpret_cast<const int4*>(y + s0);
        #pragma unroll
        for (int i = 0; i < 10; ++i) {
            a[4 * i + 0] = q[i].x; a[4 * i + 1] = q[i].y;
            a[4 * i + 2] = q[i].z; a[4 * i + 3] = q[i].w;
        }
        yc[0] = yv.x; yc[1] = yv.y; yc[2] = yv.z; yc[3] = yv.w;
    } else {
        #pragma unroll
        for (int k = 0; k < 4; ++k) {
            int idx = s0 + k;
            if (idx < B) {
                yc[k] = y[idx];
                for (int j = 0; j < 10; ++j) a[k * 10 + j] = logit[(size_t)idx * 10 + j];
            } else {
                yc[k] = -1;
                for (int j = 0; j < 10; ++j) a[k * 10 + j] = 0.f;
            }
        }
    }
}

// ============================ FUSED COOPERATIVE ============================
__global__ __launch_bounds__(FTH, 2) void k_fused(
    const float* __restrict__ logit, const int* __restrict__ y,
    const int* __restrict__ label_freq,
    float* __restrict__ out, float* __restrict__ ws, int B)
{
    cg::grid_group grid = cg::this_grid();

    __shared__ float tile[FTH * 20];      // 40 KB output-staging chunk (1024 rows)
    __shared__ float Dall[PGD][100];
    __shared__ float shT[100];
    __shared__ float shCnt[10];
    __shared__ float shCn[10];
    __shared__ float wtab[NSUB][100];
    __shared__ float ctab[NSUB][10];
    __shared__ int   lf[10];
    __shared__ float wsum[8];

    const int tid = threadIdx.x;
    float* counts_tab = ws + WS_COUNTS;
    float* S_tab      = ws + WS_STAB;

    const size_t ftot = (size_t)B * 10;
    float* news_out = out + 1;
    float* copy_out = out + 1 + ftot;

    // ---- out[0] := 0, device-scope (all ops on out[0] are atomics) ----
    if (blockIdx.x == 0 && tid == 0) atomicExch(out, 0.f);
    if (tid < 10) lf[tid] = label_freq[tid];

    // ---- load this thread's 8 contiguous rows into registers (once!) ----
    const int s0 = (blockIdx.x * FTH + tid) * FSP;
    float a[80];
    int   yc[8];
    load4(logit, y, s0,     B, a,      yc);
    load4(logit, y, s0 + 4, B, a + 40, yc + 4);

    // ---- copy output now: lane-linear float4 stream (L2-warm re-read) ----
    {
        const size_t fbase = (size_t)blockIdx.x * (FTS * 10);
        #pragma unroll
        for (int i = 0; i < 20; ++i) {
            size_t fi = fbase + (size_t)(tid + i * FTH) * 4;
            if (fi + 4 <= ftot) {
                float4 v = *reinterpret_cast<const float4*>(logit + fi);
                *reinterpret_cast<float4*>(copy_out + fi) = v;
            } else {
                for (size_t e = fi; e < ftot; ++e) copy_out[e] = logit[e];
            }
        }
    }

    // ---- 10 PGD steps, all from registers ----
    for (int t = 1; t <= PGD; ++t) {
        for (int i = tid; i < NSUB * 100; i += FTH) (&wtab[0][0])[i] = 0.f;
        if (t == 1) for (int i = tid; i < NSUB * 10; i += FTH) (&ctab[0][0])[i] = 0.f;
        __syncthreads();

        const int sub = ((tid >> 6) << 1) | (tid & 1);  // 0..7
        #pragma unroll
        for (int k = 0; k < FSP; ++k) {
            int c = yc[k];
            if (c < 0) continue;
            float tv[10];
            #pragma unroll
            for (int j = 0; j < 10; ++j) tv[j] = a[k * 10 + j];
            if (t >= 2) {
                #pragma unroll
                for (int j = 0; j < 10; ++j) tv[j] += Dall[t - 2][c * 10 + j];
            }
            float m = tv[0];
            #pragma unroll
            for (int j = 1; j < 10; ++j) m = fmaxf(m, tv[j]);
            float s = 0.f;
            #pragma unroll
            for (int j = 0; j < 10; ++j) { tv[j] = __expf(tv[j] - m); s += tv[j]; }
            float r = 1.f / s;
            #pragma unroll
            for (int j = 0; j < 10; ++j) unsafeAtomicAdd(&wtab[sub][c * 10 + j], tv[j] * r);
            if (t == 1) unsafeAtomicAdd(&ctab[sub][c], 1.f);
        }
        __syncthreads();

        const int tb = blockIdx.x & (NTAB - 1);
        if (tid < 100) {
            float s = 0.f;
            #pragma unroll
            for (int w = 0; w < NSUB; ++w) s += wtab[w][tid];
            unsafeAtomicAdd(&S_tab[(size_t)(t - 1) * (NTAB * 100) + (size_t)tb * 100 + tid], s);
        }
        if (t == 1 && tid < 10) {
            float s = 0.f;
            #pragma unroll
            for (int w = 0; w < NSUB; ++w) s += ctab[w][tid];
            unsafeAtomicAdd(&counts_tab[tb * 10 + tid], s);
        }
        __threadfence();
        grid.sync();
        __threadfence();

        // every block computes identical D_t -> Dall[t-1]
        table_phase(S_tab + (size_t)(t - 1) * (NTAB * 100), counts_tab,
                    (t >= 2) ? &Dall[t - 2][0] : nullptr,
                    shT, shCnt, shCn, &Dall[t - 1][0], tid);
    }

    // ---- news output: 4 chunks of 1024 rows staged in LDS, lane-linear stores ----
    float acc = 0.f;
    const size_t fbase = (size_t)blockIdx.x * (FTS * 10);
    for (int cc = 0; cc < 4; ++cc) {
        __syncthreads();
        if ((tid >> 7) == cc) {   // producers: 128 threads own this chunk's rows
            const int lt = tid & 127;
            #pragma unroll
            for (int k = 0; k < FSP; ++k) {
                int c = yc[k];
                if (c < 0) continue;
                int rrel = lt * FSP + k;          // row within chunk [0,1024)
                int sel = lf[c];                  // Dall[sel] = state after sel+1 steps
                float nv[10];
                #pragma unroll
                for (int j = 0; j < 10; ++j) nv[j] = a[k * 10 + j] + Dall[sel][c * 10 + j];
                #pragma unroll
                for (int j = 0; j < 10; ++j) tile[rrel * 10 + j] = nv[j];
                float m = nv[0];
                #pragma unroll
                for (int j = 1; j < 10; ++j) m = fmaxf(m, nv[j]);
                float s = 0.f;
                #pragma unroll
                for (int j = 0; j < 10; ++j) s += __expf(nv[j] - m);
                acc += __logf(s) + m - nv[c];
            }
        }
        __syncthreads();
        const float4* tp = reinterpret_cast<const float4*>(tile);
        #pragma unroll
        for (int i = 0; i < 5; ++i) {
            size_t fo = fbase + (size_t)cc * (FTH * 20) + (size_t)(tid + i * FTH) * 4;
            if (fo + 4 <= ftot) {
                *reinterpret_cast<float4*>(news_out + fo) = tp[tid + i * FTH];
            } else {
                for (size_t e = fo; e < ftot; ++e) news_out[e] = tile[(e - fbase - (size_t)cc * (FTH * 20))];
            }
        }
    }

    // ---- CE reduce ----
    #pragma unroll
    for (int off = 32; off > 0; off >>= 1) acc += __shfl_down(acc, off);
    if ((tid & 63) == 0) wsum[tid >> 6] = acc;
    __syncthreads();
    if (tid == 0) {
        float b = 0.f;
        #pragma unroll
        for (int w = 0; w < 8; ++w) b += wsum[w];
        unsafeAtomicAdd(out, b / (float)B);
    }
}

// ============================ FALLBACK (round 9, known-pass) ============================
__global__ __launch_bounds__(NTHR) void k_step(
    const float* __restrict__ logit, const int* __restrict__ y,
    float* __restrict__ ws, int B, int t)
{
    __shared__ float sh_D[100];
    __shared__ float shT[100];
    __shared__ float shCnt[10];
    __shared__ float shCn[10];
    __shared__ float wtab[NSUB][100];
    __shared__ float ctab[NSUB][10];

    const int tid = threadIdx.x;
    float* counts_tab = ws + WS_COUNTS;
    float* S_tab      = ws + WS_STAB;
    float* D_glob     = ws + WS_DGLOB;

    const int s0 = (blockIdx.x * NTHR + tid) * SPT;
    float a[40];
    int   yc[4];
    load4(logit, y, s0, B, a, yc);

    for (int i = tid; i < NSUB * 100; i += NTHR) (&wtab[0][0])[i] = 0.f;
    if (t == 1) for (int i = tid; i < NSUB * 10; i += NTHR) (&ctab[0][0])[i] = 0.f;

    if (t >= 2) {
        table_phase(S_tab + (size_t)(t - 2) * (NTAB * 100), counts_tab,
                    (t >= 3) ? (D_glob + (size_t)(t - 3) * 100) : nullptr,
                    shT, shCnt, shCn, sh_D, tid);
        if (blockIdx.x == 0 && tid < 100) D_glob[(size_t)(t - 2) * 100 + tid] = sh_D[tid];
    }
    __syncthreads();

    const int sub = ((tid >> 6) << 1) | (tid & 1);
    #pragma unroll
    for (int k = 0; k < SPT; ++k) {
        int c = yc[k];
        if (c < 0) continue;
        float tv[10];
        #pragma unroll
        for (int j = 0; j < 10; ++j) tv[j] = a[k * 10 + j];
        if (t >= 2) {
            #pragma unroll
            for (int j = 0; j < 10; ++j) tv[j] += sh_D[c * 10 + j];
        }
        float m = tv[0];
        #pragma unroll
        for (int j = 1; j < 10; ++j) m = fmaxf(m, tv[j]);
        float s = 0.f;
        #pragma unroll
        for (int j = 0; j < 10; ++j) { tv[j] = __expf(tv[j] - m); s += tv[j]; }
        float r = 1.f / s;
        #pragma unroll
        for (int j = 0; j < 10; ++j) unsafeAtomicAdd(&wtab[sub][c * 10 + j], tv[j] * r);
        if (t == 1) unsafeAtomicAdd(&ctab[sub][c], 1.f);
    }
    __syncthreads();

    const int tb = blockIdx.x & (NTAB - 1);
    if (tid < 100) {
        float s = 0.f;
        #pragma unroll
        for (int w = 0; w < NSUB; ++w) s += wtab[w][tid];
        unsafeAtomicAdd(&S_tab[(size_t)(t - 1) * (NTAB * 100) + (size_t)tb * 100 + tid], s);
    }
    if (t == 1 && tid < 10) {
        float s = 0.f;
        #pragma unroll
        for (int w = 0; w < NSUB; ++w) s += ctab[w][tid];
        unsafeAtomicAdd(&counts_tab[tb * 10 + tid], s);
    }
}

__global__ __launch_bounds__(NTHR) void k_final(
    const float* __restrict__ logit, const int* __restrict__ y,
    const int* __restrict__ label_freq,
    float* __restrict__ out, float* __restrict__ ws, int B)
{
    __shared__ float tile_f[TSAMP * 10];
    __shared__ int   yt[TSAMP];
    __shared__ float Dall[PGD][100];
    __shared__ float shT[100];
    __shared__ float shCnt[10];
    __shared__ float shCn[10];
    __shared__ int   lf[10];
    __shared__ float wsum[4];

    const int tid = threadIdx.x;
    float* counts_tab = ws + WS_COUNTS;
    float* S_tab      = ws + WS_STAB;
    float* D_glob     = ws + WS_DGLOB;

    const size_t fbase = (size_t)blockIdx.x * (TSAMP * 10);
    const size_t ftot  = (size_t)B * 10;
    float4 q[10];
    int4 yq;
    #pragma unroll
    for (int i = 0; i < 10; ++i) {
        size_t fi = fbase + (size_t)(tid + i * NTHR) * 4;
        if (fi + 4 <= ftot) {
            q[i] = *reinterpret_cast<const float4*>(logit + fi);
        } else {
            float e[4];
            #pragma unroll
            for (int e2 = 0; e2 < 4; ++e2) e[e2] = (fi + e2 < ftot) ? logit[fi + e2] : 0.f;
            q[i] = make_float4(e[0], e[1], e[2], e[3]);
        }
    }
    {
        int yi = blockIdx.x * TSAMP + tid * 4;
        if (yi + 4 <= B) {
            yq = *reinterpret_cast<const int4*>(y + yi);
        } else {
            yq.x = (yi < B) ? y[yi] : 0;
            yq.y = (yi + 1 < B) ? y[yi + 1] : 0;
            yq.z = (yi + 2 < B) ? y[yi + 2] : 0;
            yq.w = (yi + 3 < B) ? y[yi + 3] : 0;
        }
    }

    table_phase(S_tab + (size_t)9 * (NTAB * 100), counts_tab, D_glob + 8 * 100,
                shT, shCnt, shCn, &Dall[9][0], tid);
    for (int i = tid; i < 900; i += NTHR) Dall[i / 100][i % 100] = D_glob[i];
    if (tid < 10) lf[tid] = label_freq[tid];

    float4* tp = reinterpret_cast<float4*>(tile_f);
    #pragma unroll
    for (int i = 0; i < 10; ++i) tp[tid + i * NTHR] = q[i];
    reinterpret_cast<int4*>(yt)[tid] = yq;
    __syncthreads();

    const int vfloat = (int)((ftot - fbase < (size_t)(TSAMP * 10)) ? (ftot - fbase)
                                                                   : (size_t)(TSAMP * 10));
    float* news_out = out + 1;
    float* copy_out = out + 1 + ftot;

    for (int m = tid; m < vfloat; m += NTHR) copy_out[fbase + m] = tile_f[m];
    __syncthreads();

    float acc = 0.f;
    #pragma unroll
    for (int k = 0; k < SPT; ++k) {
        int sl = tid + k * NTHR;
        int gi = blockIdx.x * TSAMP + sl;
        if (gi >= B) break;
        int c = yt[sl];
        int sel = lf[c];
        float2* rp = reinterpret_cast<float2*>(tile_f + sl * 10);
        float nv[10];
        #pragma unroll
        for (int h = 0; h < 5; ++h) {
            float2 v = rp[h];
            nv[2 * h]     = v.x + Dall[sel][c * 10 + 2 * h];
            nv[2 * h + 1] = v.y + Dall[sel][c * 10 + 2 * h + 1];
        }
        #pragma unroll
        for (int h = 0; h < 5; ++h) rp[h] = make_float2(nv[2 * h], nv[2 * h + 1]);
        float m = nv[0];
        #pragma unroll
        for (int j = 1; j < 10; ++j) m = fmaxf(m, nv[j]);
        float s = 0.f;
        #pragma unroll
        for (int j = 0; j < 10; ++j) s += __expf(nv[j] - m);
        acc += __logf(s) + m - nv[c];
    }
    __syncthreads();

    for (int m = tid; m < vfloat; m += NTHR) news_out[fbase + m] = tile_f[m];

    #pragma unroll
    for (int off = 32; off > 0; off >>= 1) acc += __shfl_down(acc, off);
    if ((tid & 63) == 0) wsum[tid >> 6] = acc;
    __syncthreads();
    if (tid == 0)
        unsafeAtomicAdd(out, (wsum[0] + wsum[1] + wsum[2] + wsum[3]) / (float)B);
}

extern "C" void kernel_launch(void* const* d_in, const int* in_sizes, int n_in,
                              void* d_out, int out_size, void* d_ws, size_t ws_size,
                              hipStream_t stream) {
    const float* logit = (const float*)d_in[0];
    const int*   yy    = (const int*)d_in[1];
    const int*   lf    = (const int*)d_in[2];
    float* out = (float*)d_out;
    float* ws  = (float*)d_ws;
    int B = in_sizes[0] / 10;

    int fblocks = (B + FTS - 1) / FTS;   // 256 for B = 1M

    // capture-safe host-only queries: can the cooperative grid co-reside?
    int dev = 0; hipGetDevice(&dev);
    int numCU = 0;
    hipDeviceGetAttribute(&numCU, hipDeviceAttributeMultiprocessorCount, dev);
    int maxB = 0;
    hipOccupancyMaxActiveBlocksPerMultiprocessor(&maxB, (const void*)k_fused, FTH, 0);
    bool coop_ok = (maxB > 0) && ((long)maxB * (long)numCU >= (long)fblocks);

    hipLaunchKernelGGL(k_init, dim3(64), dim3(256), 0, stream, ws, out);

    if (coop_ok) {
        void* args[] = { (void*)&logit, (void*)&yy, (void*)&lf,
                         (void*)&out, (void*)&ws, (void*)&B };
        hipLaunchCooperativeKernel((const void*)k_fused, dim3(fblocks), dim3(FTH),
                                   args, 0, stream);
    } else {
        int blocks = (B + TSAMP - 1) / TSAMP;
        for (int t = 1; t <= PGD; ++t)
            hipLaunchKernelGGL(k_step, dim3(blocks), dim3(NTHR), 0, stream,
                               logit, yy, ws, B, t);
        hipLaunchKernelGGL(k_final, dim3(blocks), dim3(NTHR), 0, stream,
                           logit, yy, lf, out, ws, B);
    }
}

// Round 11
// 645.447 us; speedup vs baseline: 1.0390x; 1.0004x over previous
//
#include <hip/hip_runtime.h>
#include <hip/hip_cooperative_groups.h>

#define PGD   10
#define ALPHA 0.15f
#define NTAB  32
#define NSUB  8

// ---- fused kernel geometry ----
#define FTH   512           // threads/block
#define FSP   4             // samples/thread (contiguous rows)
#define FTS   (FTH * FSP)   // 2048 samples per block -> 512 blocks for B=1M

// ---- fallback (round-9) geometry ----
#define NTHR  256
#define SPT   4
#define TSAMP (NTHR * SPT)

// ws float layout:
//   [0,    320)    counts_tab[NTAB][10]
//   [320,  32320)  S_tab[PGD][NTAB][100]
//   [32320,33320)  D_glob[10][100]  (fallback only)
//   [33320]        barrier counter (int)
#define WS_COUNTS 0
#define WS_STAB   320
#define WS_DGLOB  32320
#define WS_BAR    33320
#define WS_ZERO_N 33324

__global__ void k_init(float* __restrict__ ws, float* __restrict__ out) {
    int i = blockIdx.x * blockDim.x + threadIdx.x;
    if (i == 0) out[0] = 0.f;
    int gs = gridDim.x * blockDim.x;
    for (int k = i; k < WS_ZERO_N; k += gs) ws[k] = 0.f;
}

__device__ __forceinline__ float aload(const float* p) {
    return __hip_atomic_load(p, __ATOMIC_RELAXED, __HIP_MEMORY_SCOPE_AGENT);
}

// fp32 table step, plain loads (fallback path; dispatch boundary = fence).
__device__ __forceinline__ void table_phase(
    const float* __restrict__ Sg, const float* __restrict__ counts_tab,
    const float* Dprev, float* shT, float* shCnt, float* shCn,
    float* shD_out, int tid)
{
    if (tid < 10) {
        float s = 0.f;
        #pragma unroll
        for (int k = 0; k < NTAB; ++k) s += counts_tab[k * 10 + tid];
        shCnt[tid] = (s == 0.f) ? 100.f : s;
    }
    if (tid < 100) {
        float s = 0.f;
        #pragma unroll
        for (int k = 0; k < NTAB; ++k) s += Sg[k * 100 + tid];
        shT[tid] = s;
    }
    __syncthreads();
    if (tid < 100) {
        int c = tid / 10, j = tid - c * 10;
        shT[tid] = shT[tid] / shCnt[c] - ((c == j) ? 1.f : 0.f);
    }
    __syncthreads();
    if (tid < 10) {  // column norms (torch-faithful: row c divided by col_norm[c])
        float s = 0.f;
        for (int cc = 0; cc < 10; ++cc) { float g = shT[cc * 10 + tid]; s += g * g; }
        shCn[tid] = sqrtf(s);
    }
    __syncthreads();
    if (tid < 100) {
        int c = tid / 10;
        float sign = (c < 4) ? -1.f : 1.f;   // SIGN_VEC = [-1]*4 + [1]*6
        float g = shT[tid] / shCn[c] * (ALPHA * sign);
        shD_out[tid] = (Dprev ? Dprev[tid] : 0.f) + g;
    }
    __syncthreads();
}

// Load 4 contiguous samples as 10 float4 + 1 int4, hoisted.
__device__ __forceinline__ void load4(const float* __restrict__ logit,
                                      const int* __restrict__ y,
                                      int s0, int B, float* a, int* yc) {
    if (s0 + 4 <= B) {
        const float4* rp = reinterpret_cast<const float4*>(logit + (size_t)s0 * 10);
        float4 q[10];
        #pragma unroll
        for (int i = 0; i < 10; ++i) q[i] = rp[i];
        int4 yv = *reinterpret_cast<const int4*>(y + s0);
        #pragma unroll
        for (int i = 0; i < 10; ++i) {
            a[4 * i + 0] = q[i].x; a[4 * i + 1] = q[i].y;
            a[4 * i + 2] = q[i].z; a[4 * i + 3] = q[i].w;
        }
        yc[0] = yv.x; yc[1] = yv.y; yc[2] = yv.z; yc[3] = yv.w;
    } else {
        #pragma unroll
        for (int k = 0; k < 4; ++k) {
            int idx = s0 + k;
            if (idx < B) {
                yc[k] = y[idx];
                for (int j = 0; j < 10; ++j) a[k * 10 + j] = logit[(size_t)idx * 10 + j];
            } else {
                yc[k] = -1;
                for (int j = 0; j < 10; ++j) a[k * 10 + j] = 0.f;
            }
        }
    }
}

// ============================ FUSED + LIGHT BARRIER ============================
__global__ __launch_bounds__(FTH, 2) void k_fused(
    const float* __restrict__ logit, const int* __restrict__ y,
    const int* __restrict__ label_freq,
    float* __restrict__ out, float* __restrict__ ws, int B)
{
    __shared__ float tile[1024 * 10];     // 40 KB output-staging chunk
    __shared__ float Dall[PGD][100];
    __shared__ float shT[100];
    __shared__ float shCnt[10];
    __shared__ float shCn[10];
    __shared__ float wtab[NSUB][100];
    __shared__ float ctab[NSUB][10];
    __shared__ int   lf[10];
    __shared__ float wsum[8];

    const int tid = threadIdx.x;
    float* counts_tab = ws + WS_COUNTS;
    float* S_tab      = ws + WS_STAB;
    int*   bar        = (int*)(ws + WS_BAR);

    const size_t ftot = (size_t)B * 10;
    float* news_out = out + 1;
    float* copy_out = out + 1 + ftot;

    if (tid < 10) lf[tid] = label_freq[tid];

    // ---- load this thread's 4 contiguous rows into registers (once) ----
    const int s0 = (blockIdx.x * FTH + tid) * FSP;
    float a[40];
    int   yc[4];
    load4(logit, y, s0, B, a, yc);

    // ---- copy output: lane-linear float4 stream (L2-warm re-read) ----
    const size_t fbase = (size_t)blockIdx.x * (FTS * 10);
    #pragma unroll
    for (int i = 0; i < 10; ++i) {     // FTS*10/4/FTH = 10
        size_t fi = fbase + (size_t)(tid + i * FTH) * 4;
        if (fi + 4 <= ftot) {
            float4 v = *reinterpret_cast<const float4*>(logit + fi);
            *reinterpret_cast<float4*>(copy_out + fi) = v;
        } else {
            for (size_t e = fi; e < ftot; ++e) copy_out[e] = logit[e];
        }
    }

    const int nblk = gridDim.x;

    // ---- 10 PGD steps, all from registers, light barriers ----
    for (int t = 1; t <= PGD; ++t) {
        for (int i = tid; i < NSUB * 100; i += FTH) (&wtab[0][0])[i] = 0.f;
        if (t == 1) for (int i = tid; i < NSUB * 10; i += FTH) (&ctab[0][0])[i] = 0.f;
        __syncthreads();

        const int sub = ((tid >> 6) << 1) | (tid & 1);  // 0..7
        #pragma unroll
        for (int k = 0; k < FSP; ++k) {
            int c = yc[k];
            if (c < 0) continue;
            float tv[10];
            #pragma unroll
            for (int j = 0; j < 10; ++j) tv[j] = a[k * 10 + j];
            if (t >= 2) {
                #pragma unroll
                for (int j = 0; j < 10; ++j) tv[j] += Dall[t - 2][c * 10 + j];
            }
            float m = tv[0];
            #pragma unroll
            for (int j = 1; j < 10; ++j) m = fmaxf(m, tv[j]);
            float s = 0.f;
            #pragma unroll
            for (int j = 0; j < 10; ++j) { tv[j] = __expf(tv[j] - m); s += tv[j]; }
            float r = 1.f / s;
            #pragma unroll
            for (int j = 0; j < 10; ++j) unsafeAtomicAdd(&wtab[sub][c * 10 + j], tv[j] * r);
            if (t == 1) unsafeAtomicAdd(&ctab[sub][c], 1.f);
        }
        __syncthreads();

        // flush: DEVICE-SCOPE atomics (coherent point, cross-XCD visible)
        const int tb = blockIdx.x & (NTAB - 1);
        if (tid < 100) {
            float s = 0.f;
            #pragma unroll
            for (int w = 0; w < NSUB; ++w) s += wtab[w][tid];
            atomicAdd(&S_tab[(size_t)(t - 1) * (NTAB * 100) + (size_t)tb * 100 + tid], s);
        }
        if (t == 1 && tid < 10) {
            float s = 0.f;
            #pragma unroll
            for (int w = 0; w < NSUB; ++w) s += ctab[w][tid];
            atomicAdd(&counts_tab[tb * 10 + tid], s);
        }

        // ---- light grid barrier #t (no threadfence, no L2 flush) ----
        __syncthreads();   // drains each wave's vmcnt (compiler waitcnt before s_barrier)
        if (tid == 0) {
            __hip_atomic_fetch_add(bar, 1, __ATOMIC_ACQ_REL, __HIP_MEMORY_SCOPE_AGENT);
            while (__hip_atomic_load(bar, __ATOMIC_ACQUIRE, __HIP_MEMORY_SCOPE_AGENT) < nblk * t)
                __builtin_amdgcn_s_sleep(16);
        }
        __syncthreads();

        // ---- table phase: agent-scope atomic loads (bypass stale L2) ----
        if (tid < 10) {
            float s = 0.f;
            #pragma unroll
            for (int k = 0; k < NTAB; ++k) s += aload(&counts_tab[k * 10 + tid]);
            shCnt[tid] = (s == 0.f) ? 100.f : s;
        }
        if (tid < 100) {
            float s = 0.f;
            const float* Sg = S_tab + (size_t)(t - 1) * (NTAB * 100);
            #pragma unroll
            for (int k = 0; k < NTAB; ++k) s += aload(&Sg[k * 100 + tid]);
            shT[tid] = s;
        }
        __syncthreads();
        if (tid < 100) {
            int c = tid / 10, j = tid - c * 10;
            shT[tid] = shT[tid] / shCnt[c] - ((c == j) ? 1.f : 0.f);
        }
        __syncthreads();
        if (tid < 10) {
            float s = 0.f;
            for (int cc = 0; cc < 10; ++cc) { float g = shT[cc * 10 + tid]; s += g * g; }
            shCn[tid] = sqrtf(s);
        }
        __syncthreads();
        if (tid < 100) {
            int c = tid / 10;
            float sign = (c < 4) ? -1.f : 1.f;
            float g = shT[tid] / shCn[c] * (ALPHA * sign);
            Dall[t - 1][tid] = ((t >= 2) ? Dall[t - 2][tid] : 0.f) + g;
        }
        __syncthreads();
    }

    // ---- news output: 2 chunks of 1024 rows staged in LDS, lane-linear stores ----
    float acc = 0.f;
    for (int cc = 0; cc < 2; ++cc) {
        __syncthreads();
        if ((tid >> 8) == cc) {   // 256 producer threads own this chunk's rows
            const int lt = tid & 255;
            #pragma unroll
            for (int k = 0; k < FSP; ++k) {
                int c = yc[k];
                if (c < 0) continue;
                int rrel = lt * FSP + k;          // row within chunk [0,1024)
                int sel = lf[c];                  // Dall[sel] = state after sel+1 steps
                float nv[10];
                #pragma unroll
                for (int j = 0; j < 10; ++j) nv[j] = a[k * 10 + j] + Dall[sel][c * 10 + j];
                #pragma unroll
                for (int j = 0; j < 10; ++j) tile[rrel * 10 + j] = nv[j];
                float m = nv[0];
                #pragma unroll
                for (int j = 1; j < 10; ++j) m = fmaxf(m, nv[j]);
                float s = 0.f;
                #pragma unroll
                for (int j = 0; j < 10; ++j) s += __expf(nv[j] - m);
                acc += __logf(s) + m - nv[c];
            }
        }
        __syncthreads();
        const float4* tp = reinterpret_cast<const float4*>(tile);
        #pragma unroll
        for (int i = 0; i < 5; ++i) {
            size_t fo = fbase + (size_t)cc * 10240 + (size_t)(tid + i * FTH) * 4;
            if (fo + 4 <= ftot) {
                *reinterpret_cast<float4*>(news_out + fo) = tp[tid + i * FTH];
            } else {
                size_t lbase = fbase + (size_t)cc * 10240;
                for (size_t e = fo; e < ftot; ++e) news_out[e] = tile[e - lbase];
            }
        }
    }

    // ---- CE reduce ----
    #pragma unroll
    for (int off = 32; off > 0; off >>= 1) acc += __shfl_down(acc, off);
    if ((tid & 63) == 0) wsum[tid >> 6] = acc;
    __syncthreads();
    if (tid == 0) {
        float b = 0.f;
        #pragma unroll
        for (int w = 0; w < 8; ++w) b += wsum[w];
        atomicAdd(out, b / (float)B);
    }
}

// ============================ FALLBACK (round 9, known-pass) ============================
__global__ __launch_bounds__(NTHR) void k_step(
    const float* __restrict__ logit, const int* __restrict__ y,
    float* __restrict__ ws, int B, int t)
{
    __shared__ float sh_D[100];
    __shared__ float shT[100];
    __shared__ float shCnt[10];
    __shared__ float shCn[10];
    __shared__ float wtab[NSUB][100];
    __shared__ float ctab[NSUB][10];

    const int tid = threadIdx.x;
    float* counts_tab = ws + WS_COUNTS;
    float* S_tab      = ws + WS_STAB;
    float* D_glob     = ws + WS_DGLOB;

    const int s0 = (blockIdx.x * NTHR + tid) * SPT;
    float a[40];
    int   yc[4];
    load4(logit, y, s0, B, a, yc);

    for (int i = tid; i < NSUB * 100; i += NTHR) (&wtab[0][0])[i] = 0.f;
    if (t == 1) for (int i = tid; i < NSUB * 10; i += NTHR) (&ctab[0][0])[i] = 0.f;

    if (t >= 2) {
        table_phase(S_tab + (size_t)(t - 2) * (NTAB * 100), counts_tab,
                    (t >= 3) ? (D_glob + (size_t)(t - 3) * 100) : nullptr,
                    shT, shCnt, shCn, sh_D, tid);
        if (blockIdx.x == 0 && tid < 100) D_glob[(size_t)(t - 2) * 100 + tid] = sh_D[tid];
    }
    __syncthreads();

    const int sub = ((tid >> 6) << 1) | (tid & 1);
    #pragma unroll
    for (int k = 0; k < SPT; ++k) {
        int c = yc[k];
        if (c < 0) continue;
        float tv[10];
        #pragma unroll
        for (int j = 0; j < 10; ++j) tv[j] = a[k * 10 + j];
        if (t >= 2) {
            #pragma unroll
            for (int j = 0; j < 10; ++j) tv[j] += sh_D[c * 10 + j];
        }
        float m = tv[0];
        #pragma unroll
        for (int j = 1; j < 10; ++j) m = fmaxf(m, tv[j]);
        float s = 0.f;
        #pragma unroll
        for (int j = 0; j < 10; ++j) { tv[j] = __expf(tv[j] - m); s += tv[j]; }
        float r = 1.f / s;
        #pragma unroll
        for (int j = 0; j < 10; ++j) unsafeAtomicAdd(&wtab[sub][c * 10 + j], tv[j] * r);
        if (t == 1) unsafeAtomicAdd(&ctab[sub][c], 1.f);
    }
    __syncthreads();

    const int tb = blockIdx.x & (NTAB - 1);
    if (tid < 100) {
        float s = 0.f;
        #pragma unroll
        for (int w = 0; w < NSUB; ++w) s += wtab[w][tid];
        unsafeAtomicAdd(&S_tab[(size_t)(t - 1) * (NTAB * 100) + (size_t)tb * 100 + tid], s);
    }
    if (t == 1 && tid < 10) {
        float s = 0.f;
        #pragma unroll
        for (int w = 0; w < NSUB; ++w) s += ctab[w][tid];
        unsafeAtomicAdd(&counts_tab[tb * 10 + tid], s);
    }
}

__global__ __launch_bounds__(NTHR) void k_final(
    const float* __restrict__ logit, const int* __restrict__ y,
    const int* __restrict__ label_freq,
    float* __restrict__ out, float* __restrict__ ws, int B)
{
    __shared__ float tile_f[TSAMP * 10];
    __shared__ int   yt[TSAMP];
    __shared__ float Dall[PGD][100];
    __shared__ float shT[100];
    __shared__ float shCnt[10];
    __shared__ float shCn[10];
    __shared__ int   lf[10];
    __shared__ float wsum[4];

    const int tid = threadIdx.x;
    float* counts_tab = ws + WS_COUNTS;
    float* S_tab      = ws + WS_STAB;
    float* D_glob     = ws + WS_DGLOB;

    const size_t fbase = (size_t)blockIdx.x * (TSAMP * 10);
    const size_t ftot  = (size_t)B * 10;
    float4 q[10];
    int4 yq;
    #pragma unroll
    for (int i = 0; i < 10; ++i) {
        size_t fi = fbase + (size_t)(tid + i * NTHR) * 4;
        if (fi + 4 <= ftot) {
            q[i] = *reinterpret_cast<const float4*>(logit + fi);
        } else {
            float e[4];
            #pragma unroll
            for (int e2 = 0; e2 < 4; ++e2) e[e2] = (fi + e2 < ftot) ? logit[fi + e2] : 0.f;
            q[i] = make_float4(e[0], e[1], e[2], e[3]);
        }
    }
    {
        int yi = blockIdx.x * TSAMP + tid * 4;
        if (yi + 4 <= B) {
            yq = *reinterpret_cast<const int4*>(y + yi);
        } else {
            yq.x = (yi < B) ? y[yi] : 0;
            yq.y = (yi + 1 < B) ? y[yi + 1] : 0;
            yq.z = (yi + 2 < B) ? y[yi + 2] : 0;
            yq.w = (yi + 3 < B) ? y[yi + 3] : 0;
        }
    }

    table_phase(S_tab + (size_t)9 * (NTAB * 100), counts_tab, D_glob + 8 * 100,
                shT, shCnt, shCn, &Dall[9][0], tid);
    for (int i = tid; i < 900; i += NTHR) Dall[i / 100][i % 100] = D_glob[i];
    if (tid < 10) lf[tid] = label_freq[tid];

    float4* tp = reinterpret_cast<float4*>(tile_f);
    #pragma unroll
    for (int i = 0; i < 10; ++i) tp[tid + i * NTHR] = q[i];
    reinterpret_cast<int4*>(yt)[tid] = yq;
    __syncthreads();

    const int vfloat = (int)((ftot - fbase < (size_t)(TSAMP * 10)) ? (ftot - fbase)
                                                                   : (size_t)(TSAMP * 10));
    float* news_out = out + 1;
    float* copy_out = out + 1 + ftot;

    for (int m = tid; m < vfloat; m += NTHR) copy_out[fbase + m] = tile_f[m];
    __syncthreads();

    float acc = 0.f;
    #pragma unroll
    for (int k = 0; k < SPT; ++k) {
        int sl = tid + k * NTHR;
        int gi = blockIdx.x * TSAMP + sl;
        if (gi >= B) break;
        int c = yt[sl];
        int sel = lf[c];
        float2* rp = reinterpret_cast<float2*>(tile_f + sl * 10);
        float nv[10];
        #pragma unroll
        for (int h = 0; h < 5; ++h) {
            float2 v = rp[h];
            nv[2 * h]     = v.x + Dall[sel][c * 10 + 2 * h];
            nv[2 * h + 1] = v.y + Dall[sel][c * 10 + 2 * h + 1];
        }
        #pragma unroll
        for (int h = 0; h < 5; ++h) rp[h] = make_float2(nv[2 * h], nv[2 * h + 1]);
        float m = nv[0];
        #pragma unroll
        for (int j = 1; j < 10; ++j) m = fmaxf(m, nv[j]);
        float s = 0.f;
        #pragma unroll
        for (int j = 0; j < 10; ++j) s += __expf(nv[j] - m);
        acc += __logf(s) + m - nv[c];
    }
    __syncthreads();

    for (int m = tid; m < vfloat; m += NTHR) news_out[fbase + m] = tile_f[m];

    #pragma unroll
    for (int off = 32; off > 0; off >>= 1) acc += __shfl_down(acc, off);
    if ((tid & 63) == 0) wsum[tid >> 6] = acc;
    __syncthreads();
    if (tid == 0)
        unsafeAtomicAdd(out, (wsum[0] + wsum[1] + wsum[2] + wsum[3]) / (float)B);
}

extern "C" void kernel_launch(void* const* d_in, const int* in_sizes, int n_in,
                              void* d_out, int out_size, void* d_ws, size_t ws_size,
                              hipStream_t stream) {
    const float* logit = (const float*)d_in[0];
    const int*   yy    = (const int*)d_in[1];
    const int*   lf    = (const int*)d_in[2];
    float* out = (float*)d_out;
    float* ws  = (float*)d_ws;
    int B = in_sizes[0] / 10;

    int fblocks = (B + FTS - 1) / FTS;   // 512 for B = 1M

    // capture-safe host-only queries: can the cooperative grid co-reside?
    int dev = 0; hipGetDevice(&dev);
    int numCU = 0;
    hipDeviceGetAttribute(&numCU, hipDeviceAttributeMultiprocessorCount, dev);
    int maxB = 0;
    hipOccupancyMaxActiveBlocksPerMultiprocessor(&maxB, (const void*)k_fused, FTH, 0);
    bool coop_ok = (maxB > 0) && ((long)maxB * (long)numCU >= (long)fblocks);

    hipLaunchKernelGGL(k_init, dim3(64), dim3(256), 0, stream, ws, out);

    if (coop_ok) {
        void* args[] = { (void*)&logit, (void*)&yy, (void*)&lf,
                         (void*)&out, (void*)&ws, (void*)&B };
        hipLaunchCooperativeKernel((const void*)k_fused, dim3(fblocks), dim3(FTH),
                                   args, 0, stream);
    } else {
        int blocks = (B + TSAMP - 1) / TSAMP;
        for (int t = 1; t <= PGD; ++t)
            hipLaunchKernelGGL(k_step, dim3(blocks), dim3(NTHR), 0, stream,
                               logit, yy, ws, B, t);
        hipLaunchKernelGGL(k_final, dim3(blocks), dim3(NTHR), 0, stream,
                           logit, yy, lf, out, ws, B);
    }
}